// Round 8
// baseline (126.239 us; speedup 1.0000x reference)
//
#include <hip/hip_runtime.h>
#include <hip/hip_bf16.h>
#include <stdint.h>

typedef __attribute__((ext_vector_type(8))) _Float16 half8_t;
typedef __attribute__((ext_vector_type(4))) _Float16 half4_t;
typedef __attribute__((ext_vector_type(2))) _Float16 half2_t;
typedef __attribute__((ext_vector_type(16))) float f32x16;

#define DIM 64
#define NKH 156             // (i, 16-aligned j-block) groups, K=16 each
#define NSTEP 78            // NKH/2 K=32 steps
#define BM 256              // rows/block; 4 waves x (M=64, N=64)
#define XS_STRIDE 68        // halves

// ---- static pair schedule: for i ascending, j-blocks (i+1)>>4 .. 3 ----
struct SchedT { int i[NKH]; int j0[NKH]; };
constexpr SchedT make_sched() {
    SchedT s{};
    int n = 0;
    for (int i = 0; i < 64; ++i)
        for (int jb = (i + 1) >> 4; jb < 4; ++jb) { s.i[n] = i; s.j0[n] = jb * 16; ++n; }
    return s;
}
constexpr SchedT SC = make_sched();

// runtime copy of the same enumeration (for wpack)
__device__ inline void kg_to_ij(int kg, int& io, int& jo) {
    int cum = 0; io = 0; jo = 0;
    for (int ii = 0; ii < 64; ++ii) {
        int jb0 = (ii + 1) >> 4;
        int nb = 4 - jb0;
        if (kg >= cum && kg < cum + nb) { io = ii; jo = (jb0 + (kg - cum)) * 16; }
        cum += nb;
    }
}

// Pack w1 -> fp16 B-fragments. Chunk c = s*4 + t*2 + h (t = n-tile of 32, h = k-half).
// Element off = (c*64 + lane)*8 + e == id; lane holds B[k=(lane>>5)*8+e][n=t*32+(lane&31)]
// for group kg = s*2 + h, j = j0(kg) + k.
__global__ void wpack_kernel(const float* __restrict__ w1,
                             _Float16* __restrict__ w_h) {
    int id = blockIdx.x * 256 + threadIdx.x;
    if (id >= NSTEP * 4 * 64 * 8) return;
    int e    = id & 7;
    int lane = (id >> 3) & 63;
    int c    = id >> 9;
    int s    = c >> 2;
    int t    = (c >> 1) & 1;
    int h    = c & 1;
    int kg   = s * 2 + h;
    int i, j0;
    kg_to_ij(kg, i, j0);
    int j = j0 + ((lane >> 5) << 3) + e;
    int n = t * 32 + (lane & 31);
    float w = 0.0f;
    if (j > i) {
        int p = i * DIM - (i * (i + 1)) / 2 + (j - i - 1);
        w = w1[p * DIM + n];
    }
    w_h[id] = (_Float16)w;
}

// A-fragment for compile-time group KG, m-tile MT: 8 products from registers.
// xr[MT][c] = x_dw[c ^ (hi?4:0)] so all array indices are compile-time constants.
template<int KG, int MT>
__device__ __forceinline__ half8_t aprod(const uint32_t (&xr)[2][32], bool hi) {
    constexpr int I  = SC.i[KG];
    constexpr int J0 = SC.j0[KG];
    constexpr int DI = I >> 1;
    constexpr int DJ = J0 >> 1;   // 8-aligned
    uint32_t dwi = hi ? xr[MT][DI ^ 4] : xr[MT][DI];
    half2_t hv = __builtin_bit_cast(half2_t, dwi);
    _Float16 xi = hv[I & 1];
    half2_t xi2 = {xi, xi};
    half8_t r;
    half2_t* rp = reinterpret_cast<half2_t*>(&r);
    #pragma unroll
    for (int e2 = 0; e2 < 4; ++e2) {
        half2_t xj = __builtin_bit_cast(half2_t, xr[MT][DJ + e2]);
        rp[e2] = xi2 * xj;
    }
    return r;
}

template<int S>
struct Step {
    static __device__ __forceinline__ void run(const uint32_t (&xr)[2][32],
                                               half8_t (&b)[3][4],
                                               f32x16 (&acc)[2][2],
                                               const half8_t* wl, bool hi) {
        constexpr int SP = (S + 2 < NSTEP) ? S + 2 : NSTEP - 1;
        // issue B-loads for step S+2 (plain loads: compiler inserts counted vmcnt)
        #pragma unroll
        for (int t = 0; t < 4; ++t)
            b[(S + 2) % 3][t] = wl[(SP * 4 + t) * 64];

        // A-fragments for step S (pure register VALU; hides under loads)
        half8_t ah0[2], ah1[2];
        ah0[0] = aprod<S * 2 + 0, 0>(xr, hi);
        ah0[1] = aprod<S * 2 + 0, 1>(xr, hi);
        ah1[0] = aprod<S * 2 + 1, 0>(xr, hi);
        ah1[1] = aprod<S * 2 + 1, 1>(xr, hi);

        // 8 MFMAs (32x32x16): two K=16 halves x 2 m-tiles x 2 n-tiles
        #pragma unroll
        for (int mt = 0; mt < 2; ++mt)
            #pragma unroll
            for (int nt = 0; nt < 2; ++nt)
                acc[mt][nt] = __builtin_amdgcn_mfma_f32_32x32x16_f16(
                    ah0[mt], b[S % 3][nt * 2 + 0], acc[mt][nt], 0, 0, 0);
        #pragma unroll
        for (int mt = 0; mt < 2; ++mt)
            #pragma unroll
            for (int nt = 0; nt < 2; ++nt)
                acc[mt][nt] = __builtin_amdgcn_mfma_f32_32x32x16_f16(
                    ah1[mt], b[S % 3][nt * 2 + 1], acc[mt][nt], 0, 0, 0);

        Step<S + 1>::run(xr, b, acc, wl, hi);
    }
};
template<>
struct Step<NSTEP> {
    static __device__ __forceinline__ void run(const uint32_t (&)[2][32], half8_t (&)[3][4],
                                               f32x16 (&)[2][2], const half8_t*, bool) {}
};

__global__ __launch_bounds__(256, 2)
void prodres_kernel(const float* __restrict__ x,
                    const _Float16* __restrict__ w_h,
                    float* __restrict__ out) {
    __shared__ _Float16 xs[BM * XS_STRIDE];   // 34.8 KB

    const int t    = threadIdx.x;
    const int lane = t & 63;
    const int wave = t >> 6;
    const bool hi  = (lane >> 5) & 1;
    const long brow = (long)blockIdx.x * BM;

    // stage x tile [BM][64] -> xs fp16 (coalesced float4 reads)
    #pragma unroll
    for (int it = 0; it < 16; ++it) {
        int row = it * 16 + (t >> 4);
        int c   = (t & 15) * 4;
        float4 v = *reinterpret_cast<const float4*>(x + (brow + row) * DIM + c);
        half4_t hq;
        hq[0] = (_Float16)v.x; hq[1] = (_Float16)v.y;
        hq[2] = (_Float16)v.z; hq[3] = (_Float16)v.w;
        *reinterpret_cast<half4_t*>(&xs[row * XS_STRIDE + c]) = hq;
    }
    __syncthreads();

    // fill per-lane x registers, XOR-permuted: xr[mt][c] = x_dw[c ^ (hi?4:0)]
    uint32_t xr[2][32];
    #pragma unroll
    for (int mt = 0; mt < 2; ++mt) {
        int row = wave * 64 + mt * 32 + (lane & 31);
        const uint32_t* rp = reinterpret_cast<const uint32_t*>(&xs[row * XS_STRIDE]);
        #pragma unroll
        for (int c2 = 0; c2 < 16; ++c2) {
            int src = (2 * c2) ^ (hi ? 4 : 0);
            uint64_t v = *reinterpret_cast<const uint64_t*>(rp + src);  // ds_read_b64
            xr[mt][2 * c2]     = (uint32_t)v;
            xr[mt][2 * c2 + 1] = (uint32_t)(v >> 32);
        }
    }

    f32x16 acc[2][2];
    #pragma unroll
    for (int mt = 0; mt < 2; ++mt)
        #pragma unroll
        for (int nt = 0; nt < 2; ++nt)
            #pragma unroll
            for (int q = 0; q < 16; ++q) acc[mt][nt][q] = 0.0f;

    const half8_t* wl = reinterpret_cast<const half8_t*>(w_h) + lane;
    half8_t b[3][4];

    // prologue: load steps 0 and 1
    #pragma unroll
    for (int tt = 0; tt < 4; ++tt) b[0][tt] = wl[tt * 64];
    #pragma unroll
    for (int tt = 0; tt < 4; ++tt) b[1][tt] = wl[(4 + tt) * 64];

    Step<0>::run(xr, b, acc, wl, hi);

    // epilogue: C/D 32x32 layout col=lane&31, row=(q&3)+8*(q>>2)+4*(lane>>5); fp32 residual
    const int hib = hi ? 4 : 0;
    #pragma unroll
    for (int mt = 0; mt < 2; ++mt)
        #pragma unroll
        for (int q = 0; q < 16; ++q) {
            int rit = (q & 3) + 8 * (q >> 2) + hib;
            long row = brow + wave * 64 + mt * 32 + rit;
            #pragma unroll
            for (int nt = 0; nt < 2; ++nt) {
                int col = nt * 32 + (lane & 31);
                out[row * DIM + col] = acc[mt][nt][q] + x[row * DIM + col];
            }
        }
}

extern "C" void kernel_launch(void* const* d_in, const int* in_sizes, int n_in,
                              void* d_out, int out_size, void* d_ws, size_t ws_size,
                              hipStream_t stream) {
    const float* x  = (const float*)d_in[0];
    const float* w1 = (const float*)d_in[1];
    float* out = (float*)d_out;

    _Float16* w_h = (_Float16*)d_ws;   // NSTEP*4*512 = 159744 halves = 319 KB

    int b_total = in_sizes[0] / DIM;   // 131072

    wpack_kernel<<<(NSTEP * 4 * 64 * 8 + 255) / 256, 256, 0, stream>>>(w1, w_h);
    prodres_kernel<<<b_total / BM, 256, 0, stream>>>(x, w_h, out);
}